// Round 1
// baseline (557.618 us; speedup 1.0000x reference)
//
#include <hip/hip_runtime.h>

// ---------------------------------------------------------------------------
// PhysNet stack, MI355X. Key transform: scatter-add of pair messages
//   proto[i] = h_self[i] + fmtab[i] * (S[i] @ W_gate),
//   S[i] = sum of radial rows over all pair-slots hitting atom i (module-invariant)
// so ALL per-pair GEMMs/gathers/scatters collapse into one radial scatter (S)
// plus per-atom GEMM chains (16 x [*,128]@[128,128] bf16 MFMA per module).
// ---------------------------------------------------------------------------

#define LN2F 0.69314718055994530942f
#define MOD_STRIDE (15 * 16384 + 8192) // 15 FxF mats + 1 gate (64x128) per module

using short8  = __attribute__((ext_vector_type(8))) short;
using float4v = __attribute__((ext_vector_type(4))) float;

__device__ __forceinline__ float sspf(float x) {
  // softplus(x) - ln2, numerically stable
  float ax = fabsf(x);
  return fmaxf(x, 0.0f) + __logf(1.0f + __expf(-ax)) - LN2F;
}

__device__ __forceinline__ unsigned short f2bf(float x) {
  unsigned int u = __float_as_uint(x);
  u += 0x7fffu + ((u >> 16) & 1u);   // round-to-nearest-even
  return (unsigned short)(u >> 16);
}

// ---------------------------------------------------------------------------
// S scatter: S[i, :64] += radial[p, :64] for each slot (s,p) with idx12[s,p]==i
// wave-per-pair, lane-per-column.
// ---------------------------------------------------------------------------
__global__ __launch_bounds__(256) void scatter_s_kernel(const float* __restrict__ radial,
                                                        const int* __restrict__ idx,
                                                        float* __restrict__ S, int P) {
  int lane = threadIdx.x & 63;
  int wave = blockIdx.x * 4 + (threadIdx.x >> 6);
  int nw   = gridDim.x * 4;
  for (int p = wave; p < P; p += nw) {
    float v = radial[(size_t)p * 64 + lane];
    int i0 = idx[p];
    int i1 = idx[P + p];
    atomicAdd(&S[(size_t)i0 * 64 + lane], v);
    atomicAdd(&S[(size_t)i1 * 64 + lane], v);
  }
}

// ---------------------------------------------------------------------------
// Weight prep: transpose fp32 W[k][n] -> bf16 Wt[n][k] (dense row-major, n-major)
// ---------------------------------------------------------------------------
struct PrepArgs {
  const float* src[80];
  int off[80];
  int isgate[80];
  int nmats;
};

__global__ __launch_bounds__(256) void prep_weights(PrepArgs A, unsigned short* __restrict__ Wt) {
  int m = blockIdx.x;
  const float* s = A.src[m];
  unsigned short* d = Wt + A.off[m];
  if (!A.isgate[m]) {
    for (int i = threadIdx.x; i < 16384; i += 256) {
      int k = i >> 7, n = i & 127;      // src is [128 k][128 n], reads coalesced over n
      d[n * 128 + k] = f2bf(s[i]);
    }
  } else {
    for (int i = threadIdx.x; i < 8192; i += 256) {
      int k = i >> 7, n = i & 127;      // src [64 k][128 n]
      d[n * 64 + k] = f2bf(s[i]);
    }
  }
}

// ---------------------------------------------------------------------------
// Module kernel: 32 rows/block, 4 waves; wave (g,c) = rows 16g..16g+15, cols 64c..64c+63
// ---------------------------------------------------------------------------
struct ModArgs {
  const float* feat_in;
  float* feat_out;
  const float* S;
  const unsigned short* wt;   // module's transposed bf16 weights
  const float* bias[17];      // [0]=b_J [1]=b_I [2..7]=ri_b1/b2 x3 [8]=b_int
                              // [9..12]=ra_b1/b2 x2 [13,14]=ro_b1/b2 [15]=gvec [16]=W_out
  const float* b_out;         // scalar ptr
  float* energy;              // d_out (N floats)
  int first;
};

// GEMM: rows (arow..arow+15) of sA (stride 136) x staged Wt (stride 136), K=128,
// cols 64c+16f+lane16. Verified gfx950 layouts: A[m=l16][k=quad*8+j], B[k][n=l16],
// C/D col=l16, row=quad*4+reg.
__device__ __forceinline__ void gemm128(const unsigned short* sA_, const unsigned short* sW,
                                        int arow, int c, int l16, int quad, float4v acc[4]) {
  const unsigned short* ar = sA_ + (arow + l16) * 136 + quad * 8;
  short8 a0 = *(const short8*)(ar);
  short8 a1 = *(const short8*)(ar + 32);
  short8 a2 = *(const short8*)(ar + 64);
  short8 a3 = *(const short8*)(ar + 96);
#pragma unroll
  for (int f = 0; f < 4; ++f) {
    const unsigned short* br = sW + (64 * c + 16 * f + l16) * 136 + quad * 8;
    acc[f] = __builtin_amdgcn_mfma_f32_16x16x32_bf16(a0, *(const short8*)(br), acc[f], 0, 0, 0);
    acc[f] = __builtin_amdgcn_mfma_f32_16x16x32_bf16(a1, *(const short8*)(br + 32), acc[f], 0, 0, 0);
    acc[f] = __builtin_amdgcn_mfma_f32_16x16x32_bf16(a2, *(const short8*)(br + 64), acc[f], 0, 0, 0);
    acc[f] = __builtin_amdgcn_mfma_f32_16x16x32_bf16(a3, *(const short8*)(br + 96), acc[f], 0, 0, 0);
  }
}

// Gate GEMM: K=64, A from sS (stride 72), W_gate^T staged at stride 72.
__device__ __forceinline__ void gemm64(const unsigned short* sS_, const unsigned short* sW,
                                       int arow, int c, int l16, int quad, float4v acc[4]) {
  const unsigned short* ar = sS_ + (arow + l16) * 72 + quad * 8;
  short8 a0 = *(const short8*)(ar);
  short8 a1 = *(const short8*)(ar + 32);
#pragma unroll
  for (int f = 0; f < 4; ++f) {
    const unsigned short* br = sW + (64 * c + 16 * f + l16) * 72 + quad * 8;
    acc[f] = __builtin_amdgcn_mfma_f32_16x16x32_bf16(a0, *(const short8*)(br), acc[f], 0, 0, 0);
    acc[f] = __builtin_amdgcn_mfma_f32_16x16x32_bf16(a1, *(const short8*)(br + 32), acc[f], 0, 0, 0);
  }
}

__device__ __forceinline__ void stage_mat(const unsigned short* wt, unsigned short* sWt,
                                          int t, int tid) {
  __syncthreads();
  const uint4* g4 = (const uint4*)(wt + t * 16384);
#pragma unroll
  for (int i = 0; i < 8; ++i) {
    int cl = tid + i * 256;           // 16B chunk id, 0..2047
    int n = cl >> 4, ch = cl & 15;
    *(uint4*)(&sWt[n * 136 + ch * 8]) = g4[cl];   // pad stride 136 breaks bank conflicts
  }
  __syncthreads();
}

__device__ __forceinline__ void stage_gate(const unsigned short* wt, unsigned short* sWt, int tid) {
  __syncthreads();
  const uint4* g4 = (const uint4*)(wt + 15 * 16384);
#pragma unroll
  for (int i = 0; i < 4; ++i) {
    int cl = tid + i * 256;           // 0..1023
    int n = cl >> 3, ch = cl & 7;
    *(uint4*)(&sWt[n * 72 + ch * 8]) = g4[cl];
  }
  __syncthreads();
}

__device__ __forceinline__ void write_ssp_A(unsigned short* sA_, const float4v v[4],
                                            int arow, int c, int l16, int quad) {
#pragma unroll
  for (int f = 0; f < 4; ++f)
#pragma unroll
    for (int r = 0; r < 4; ++r)
      sA_[(arow + quad * 4 + r) * 136 + 64 * c + 16 * f + l16] = f2bf(sspf(v[f][r]));
}

__global__ __launch_bounds__(256) void mod_kernel(ModArgs A) {
  __shared__ __align__(16) unsigned short sWt[128 * 136];
  __shared__ __align__(16) unsigned short sA[32 * 136];
  __shared__ __align__(16) unsigned short sS[32 * 72];
  __shared__ float sBias[17 * 128];
  __shared__ float sE[32];

  const int tid  = threadIdx.x;
  const int row0 = blockIdx.x * 32;
  const int lane = tid & 63;
  const int w    = tid >> 6;
  const int g    = w >> 1;       // row group
  const int c    = w & 1;        // col half
  const int l16  = lane & 15;
  const int quad = lane >> 4;
  const int arow = 16 * g;

  // ---- cooperative loads (biases, S tile as bf16, A = ssp(feat) as bf16)
  for (int i = tid; i < 17 * 128; i += 256)
    sBias[i] = A.bias[i >> 7][i & 127];
  for (int i = tid; i < 32 * 64; i += 256) {
    int r = i >> 6, k = i & 63;
    sS[r * 72 + k] = f2bf(A.S[(size_t)(row0 + r) * 64 + k]);
  }
  for (int i = tid; i < 32 * 128; i += 256) {
    int r = i >> 7, k = i & 127;
    sA[r * 136 + k] = f2bf(sspf(A.feat_in[(size_t)(row0 + r) * 128 + k]));
  }
  if (tid < 32) sE[tid] = 0.0f;

  const float4v Z = {0.f, 0.f, 0.f, 0.f};
  float4v fm[4], hs[4], xf[4], yf[4], t4[4];

  // ---- fmtab = ssp(ssp(feat) @ W_J + b_J)   (mat 0)
  stage_mat(A.wt, sWt, 0, tid);
  fm[0] = fm[1] = fm[2] = fm[3] = Z;
  gemm128(sA, sWt, arow, c, l16, quad, fm);
#pragma unroll
  for (int f = 0; f < 4; ++f) {
    float bb = sBias[0 * 128 + 64 * c + 16 * f + l16];
#pragma unroll
    for (int r = 0; r < 4; ++r) fm[f][r] = sspf(fm[f][r] + bb);
  }

  // ---- h_self = ssp(ssp(feat) @ W_I + b_I)   (mat 1)
  stage_mat(A.wt, sWt, 1, tid);
  hs[0] = hs[1] = hs[2] = hs[3] = Z;
  gemm128(sA, sWt, arow, c, l16, quad, hs);
#pragma unroll
  for (int f = 0; f < 4; ++f) {
    float bb = sBias[1 * 128 + 64 * c + 16 * f + l16];
#pragma unroll
    for (int r = 0; r < 4; ++r) hs[f][r] = sspf(hs[f][r] + bb);
  }

  // ---- G = S @ W_gate ; proto = fm*G + h_self
  stage_gate(A.wt, sWt, tid);
  t4[0] = t4[1] = t4[2] = t4[3] = Z;
  gemm64(sS, sWt, arow, c, l16, quad, t4);
#pragma unroll
  for (int f = 0; f < 4; ++f)
#pragma unroll
    for (int r = 0; r < 4; ++r) xf[f][r] = fm[f][r] * t4[f][r] + hs[f][r];
  write_ssp_A(sA, xf, arow, c, l16, quad);

  // ---- ri residual chain x3 (mats 2..7)
  for (int j = 0; j < 3; ++j) {
    stage_mat(A.wt, sWt, 2 + 2 * j, tid);
    t4[0] = t4[1] = t4[2] = t4[3] = Z;
    gemm128(sA, sWt, arow, c, l16, quad, t4);
#pragma unroll
    for (int f = 0; f < 4; ++f) {
      float bb = sBias[(2 + 2 * j) * 128 + 64 * c + 16 * f + l16];
#pragma unroll
      for (int r = 0; r < 4; ++r) t4[f][r] += bb;   // h (pre-ssp)
    }
    write_ssp_A(sA, t4, arow, c, l16, quad);        // sA = ssp(h)

    stage_mat(A.wt, sWt, 3 + 2 * j, tid);
    t4[0] = t4[1] = t4[2] = t4[3] = Z;
    gemm128(sA, sWt, arow, c, l16, quad, t4);
#pragma unroll
    for (int f = 0; f < 4; ++f) {
      float bb = sBias[(3 + 2 * j) * 128 + 64 * c + 16 * f + l16];
#pragma unroll
      for (int r = 0; r < 4; ++r) xf[f][r] += t4[f][r] + bb;
    }
    write_ssp_A(sA, xf, arow, c, l16, quad);        // sA = ssp(x)
  }

  // ---- feat2 = feat*gvec + ssp(msg) @ W_int + b_int   (mat 8)
  stage_mat(A.wt, sWt, 8, tid);
  t4[0] = t4[1] = t4[2] = t4[3] = Z;
  gemm128(sA, sWt, arow, c, l16, quad, t4);
#pragma unroll
  for (int f = 0; f < 4; ++f) {
    int col = 64 * c + 16 * f + l16;
    float bb = sBias[8 * 128 + col];
    float gv = sBias[15 * 128 + col];
#pragma unroll
    for (int r = 0; r < 4; ++r) {
      float fv = A.feat_in[(size_t)(row0 + arow + quad * 4 + r) * 128 + col];
      xf[f][r] = fv * gv + t4[f][r] + bb;
    }
  }
  write_ssp_A(sA, xf, arow, c, l16, quad);

  // ---- ra residual chain x2 (mats 9..12)
  for (int j = 0; j < 2; ++j) {
    stage_mat(A.wt, sWt, 9 + 2 * j, tid);
    t4[0] = t4[1] = t4[2] = t4[3] = Z;
    gemm128(sA, sWt, arow, c, l16, quad, t4);
#pragma unroll
    for (int f = 0; f < 4; ++f) {
      float bb = sBias[(9 + 2 * j) * 128 + 64 * c + 16 * f + l16];
#pragma unroll
      for (int r = 0; r < 4; ++r) t4[f][r] += bb;
    }
    write_ssp_A(sA, t4, arow, c, l16, quad);

    stage_mat(A.wt, sWt, 10 + 2 * j, tid);
    t4[0] = t4[1] = t4[2] = t4[3] = Z;
    gemm128(sA, sWt, arow, c, l16, quad, t4);
#pragma unroll
    for (int f = 0; f < 4; ++f) {
      float bb = sBias[(10 + 2 * j) * 128 + 64 * c + 16 * f + l16];
#pragma unroll
      for (int r = 0; r < 4; ++r) xf[f][r] += t4[f][r] + bb;
    }
    write_ssp_A(sA, xf, arow, c, l16, quad);
  }
  // xf is now feat2 (module output); keep it. ro chain runs on a copy.

  // ---- ro residual chain x1 (mats 13,14) on yf
#pragma unroll
  for (int f = 0; f < 4; ++f) yf[f] = xf[f];
  stage_mat(A.wt, sWt, 13, tid);
  t4[0] = t4[1] = t4[2] = t4[3] = Z;
  gemm128(sA, sWt, arow, c, l16, quad, t4);
#pragma unroll
  for (int f = 0; f < 4; ++f) {
    float bb = sBias[13 * 128 + 64 * c + 16 * f + l16];
#pragma unroll
    for (int r = 0; r < 4; ++r) t4[f][r] += bb;
  }
  write_ssp_A(sA, t4, arow, c, l16, quad);

  stage_mat(A.wt, sWt, 14, tid);
  t4[0] = t4[1] = t4[2] = t4[3] = Z;
  gemm128(sA, sWt, arow, c, l16, quad, t4);
#pragma unroll
  for (int f = 0; f < 4; ++f) {
    float bb = sBias[14 * 128 + 64 * c + 16 * f + l16];
#pragma unroll
    for (int r = 0; r < 4; ++r) yf[f][r] += t4[f][r] + bb;
  }

  // ---- e = ssp(yf) @ W_out + b_out (per-row dot, reduce over 16 lanes + 2 col waves)
  float p0 = 0.f, p1 = 0.f, p2 = 0.f, p3 = 0.f;
#pragma unroll
  for (int f = 0; f < 4; ++f) {
    float wv = sBias[16 * 128 + 64 * c + 16 * f + l16];
    p0 += sspf(yf[f][0]) * wv;
    p1 += sspf(yf[f][1]) * wv;
    p2 += sspf(yf[f][2]) * wv;
    p3 += sspf(yf[f][3]) * wv;
  }
#pragma unroll
  for (int off = 1; off < 16; off <<= 1) {
    p0 += __shfl_xor(p0, off, 64);
    p1 += __shfl_xor(p1, off, 64);
    p2 += __shfl_xor(p2, off, 64);
    p3 += __shfl_xor(p3, off, 64);
  }
  if (l16 == 0) {
    atomicAdd(&sE[arow + quad * 4 + 0], p0);
    atomicAdd(&sE[arow + quad * 4 + 1], p1);
    atomicAdd(&sE[arow + quad * 4 + 2], p2);
    atomicAdd(&sE[arow + quad * 4 + 3], p3);
  }

  // ---- write feat2
#pragma unroll
  for (int f = 0; f < 4; ++f)
#pragma unroll
    for (int r = 0; r < 4; ++r)
      A.feat_out[(size_t)(row0 + arow + quad * 4 + r) * 128 + 64 * c + 16 * f + l16] = xf[f][r];

  __syncthreads();
  if (tid < 32) {
    float e = sE[tid] + A.b_out[0];
    int row = row0 + tid;
    if (A.first) A.energy[row] = e;
    else         A.energy[row] += e;
  }
}

// ---------------------------------------------------------------------------
extern "C" void kernel_launch(void* const* d_in, const int* in_sizes, int n_in,
                              void* d_out, int out_size, void* d_ws, size_t ws_size,
                              hipStream_t stream) {
  const float* features = (const float*)d_in[1];
  const float* radial   = (const float*)d_in[2];
  const int*   idx12    = (const int*)  d_in[3];
  const float* W_I    = (const float*)d_in[4];
  const float* b_I    = (const float*)d_in[5];
  const float* W_J    = (const float*)d_in[6];
  const float* b_J    = (const float*)d_in[7];
  const float* W_gate = (const float*)d_in[8];
  const float* gvec   = (const float*)d_in[9];
  const float* W_int  = (const float*)d_in[10];
  const float* b_int  = (const float*)d_in[11];
  const float* ri_W1  = (const float*)d_in[12];
  const float* ri_b1  = (const float*)d_in[13];
  const float* ri_W2  = (const float*)d_in[14];
  const float* ri_b2  = (const float*)d_in[15];
  const float* ra_W1  = (const float*)d_in[16];
  const float* ra_b1  = (const float*)d_in[17];
  const float* ra_W2  = (const float*)d_in[18];
  const float* ra_b2  = (const float*)d_in[19];
  const float* ro_W1  = (const float*)d_in[20];
  const float* ro_b1  = (const float*)d_in[21];
  const float* ro_W2  = (const float*)d_in[22];
  const float* ro_b2  = (const float*)d_in[23];
  const float* W_out  = (const float*)d_in[24];
  const float* b_out  = (const float*)d_in[25];

  const int N = in_sizes[1] / 128;   // 8192
  const int P = in_sizes[3] / 2;     // 400000
  const int L = in_sizes[25];        // 5

  // ws layout (all 16B aligned): S [N*64 f32] | featA [N*128] | featB [N*128] | Wt bf16
  float* S     = (float*)d_ws;
  float* featA = S + (size_t)N * 64;
  float* featB = featA + (size_t)N * 128;
  unsigned short* Wt = (unsigned short*)(featB + (size_t)N * 128);

  hipMemsetAsync(S, 0, (size_t)N * 64 * sizeof(float), stream);

  // ---- weight prep args
  PrepArgs pa;
  int j = 0;
  for (int l = 0; l < L; ++l) {
    int base = l * MOD_STRIDE;
    const float* fx[15] = {
      W_J + l * 16384, W_I + l * 16384,
      ri_W1 + (l * 3 + 0) * 16384, ri_W2 + (l * 3 + 0) * 16384,
      ri_W1 + (l * 3 + 1) * 16384, ri_W2 + (l * 3 + 1) * 16384,
      ri_W1 + (l * 3 + 2) * 16384, ri_W2 + (l * 3 + 2) * 16384,
      W_int + l * 16384,
      ra_W1 + (l * 2 + 0) * 16384, ra_W2 + (l * 2 + 0) * 16384,
      ra_W1 + (l * 2 + 1) * 16384, ra_W2 + (l * 2 + 1) * 16384,
      ro_W1 + l * 16384, ro_W2 + l * 16384 };
    for (int t = 0; t < 15; ++t) { pa.src[j] = fx[t]; pa.off[j] = base + t * 16384; pa.isgate[j] = 0; ++j; }
    pa.src[j] = W_gate + l * 8192; pa.off[j] = base + 15 * 16384; pa.isgate[j] = 1; ++j;
  }
  pa.nmats = j;
  prep_weights<<<j, 256, 0, stream>>>(pa, Wt);

  scatter_s_kernel<<<2048, 256, 0, stream>>>(radial, idx12, S, P);

  float* energies   = (float*)d_out;
  float* feat_final = energies + N;

  for (int l = 0; l < L; ++l) {
    ModArgs ma;
    ma.feat_in  = (l == 0) ? features : ((l & 1) ? featA : featB);
    ma.feat_out = (l == L - 1) ? feat_final : ((l & 1) ? featB : featA);
    ma.S  = S;
    ma.wt = Wt + (size_t)l * MOD_STRIDE;
    const float* bias[17] = {
      b_J + l * 128, b_I + l * 128,
      ri_b1 + (l * 3 + 0) * 128, ri_b2 + (l * 3 + 0) * 128,
      ri_b1 + (l * 3 + 1) * 128, ri_b2 + (l * 3 + 1) * 128,
      ri_b1 + (l * 3 + 2) * 128, ri_b2 + (l * 3 + 2) * 128,
      b_int + l * 128,
      ra_b1 + (l * 2 + 0) * 128, ra_b2 + (l * 2 + 0) * 128,
      ra_b1 + (l * 2 + 1) * 128, ra_b2 + (l * 2 + 1) * 128,
      ro_b1 + l * 128, ro_b2 + l * 128,
      gvec + l * 128, W_out + l * 128 };
    for (int q = 0; q < 17; ++q) ma.bias[q] = bias[q];
    ma.b_out  = b_out + l;
    ma.energy = energies;
    ma.first  = (l == 0);
    mod_kernel<<<N / 32, 256, 0, stream>>>(ma);
  }
}